// Round 8
// baseline (597.877 us; speedup 1.0000x reference)
//
#include <hip/hip_runtime.h>
#include <cstddef>
#include <cstdint>

// ---------------------------------------------------------------------------
// attention_net_noc: pointer-network decode step.
// R8: R3's proven 2-row/thread bodies (48 VGPR, VALUBusy 62%) + R7's
// 4-dispatch last-block-combine structure. R7's 4-row body was past the
// register knee (VGPR 84, serialized, k_p1 190us); R6 proved grid.sync is
// ~350us/barrier at this grid scale. 2 rows/thread, RPB=512, tail-guarded.
// fp32 throughout; argmax tie-break = smallest index (matches jnp.argmax).
// ---------------------------------------------------------------------------

constexpr int NJ = 1000000;
constexpr int NM = 500000;
constexpr float NEGV = -1e8f;

constexpr int BLK = 256;
constexpr int RPB = 512;                    // rows per block = 2 per thread
constexpr int GJ = (NJ + RPB - 1) / RPB;    // 1954
constexpr int GM = (NM + RPB - 1) / RPB;    // 977
constexpr int G1 = GJ + GM;                 // 2931

// ---- workspace layout (float offsets from start of d_ws) ----
constexpr int S_QKJA = 0;    // 16: ja_Wq@g1 + ja_bq
constexpr int S_QK2J = 16;   // 16: aj_Wq@e_js + aj_bq
constexpr int S_QK2M = 32;   // 16: am_Wq@e_js + am_bq
constexpr int S_EJS  = 48;   // 16: E_j[sel_j]
constexpr int S_QKMA = 64;   // 16: ma_Wq@g2 + ma_bq
constexpr int S_LOGPJ = 80;
constexpr int S_SELJ  = 81;  // stored as float (exact, < 2^24)
constexpr int S_CNT   = 88;  // 4 ints: arrive counters (zeroed by memset)
constexpr int P1J = 96;                    // GJ*17 glimpse partials (l,s[16])
constexpr int P1M = P1J + GJ * 17;         // GM*17
constexpr int P2V = P1M + GM * 17;         // GJ argmax vals (P7 reuses, GM<GJ)
constexpr int P2I = P2V + GJ;
constexpr int P2L = P2I + GJ;
constexpr size_t E_OFF = 65536;            // float offset of E_j cache
static_assert(P2L + GJ <= (int)E_OFF, "partials overflow into E cache");

typedef float v2f __attribute__((ext_vector_type(2)));

struct Params {
    const float *jobs, *machines;
    const int *mask;
    const float *jW1, *jb1, *jW2, *jb2;
    const float *mW1, *mb1, *mW2, *mb2;
    const float *aj_Wq, *aj_bq, *aj_Wr, *aj_V;
    const float *am_Wq, *am_bq, *am_Wr, *am_V;
    const float *ja_Wq, *ja_bq, *ja_Wr, *ja_V;
    const float *ma_Wq, *ma_bq, *ma_Wr, *ma_V;
    const float *g1W, *g1b, *g2W, *g2b, *last_j;
    float *S;        // smalls + partials (in ws)
    int   *cnt;      // 4 arrive counters (in ws, memset to 0 each launch)
    float *Ej, *Em;  // embedding cache (in ws; used only if CACHE)
    float *out;
};

// ---------------------------------------------------------------------------
// device helpers (fp32 numerics identical to R3)
// ---------------------------------------------------------------------------

__device__ __forceinline__ float fast_tanh(float x) {
    float e = __expf(2.0f * x);
    return 1.0f - __fdividef(2.0f, e + 1.0f);
}

__device__ __forceinline__ v2f vbc(float a) { v2f r; r.x = a; r.y = a; return r; }

// packed fma: one v_pk_fma_f32 issue slot for two fp32 FMAs (bit-identical)
__device__ __forceinline__ v2f vfma(float w, v2f b, v2f c) {
    return __builtin_elementwise_fma(vbc(w), b, c);
}
__device__ __forceinline__ v2f vfma2(v2f a, v2f b, v2f c) {
    return __builtin_elementwise_fma(a, b, c);
}
__device__ __forceinline__ v2f vtanh(v2f a) {
    v2f r; r.x = fast_tanh(a.x); r.y = fast_tanh(a.y); return r;
}

__device__ __forceinline__ void load16(const float* __restrict__ X, size_t r, float (&x)[16]) {
    const float4* p4 = reinterpret_cast<const float4*>(X) + r * 4;
    float4 a = p4[0], b = p4[1], c = p4[2], d = p4[3];
    x[0]=a.x; x[1]=a.y; x[2]=a.z; x[3]=a.w;
    x[4]=b.x; x[5]=b.y; x[6]=b.z; x[7]=b.w;
    x[8]=c.x; x[9]=c.y; x[10]=c.z; x[11]=c.w;
    x[12]=d.x; x[13]=d.y; x[14]=d.z; x[15]=d.w;
}

// load rows rA,rB packed feature-wise into v2f lanes (.x=rowA, .y=rowB)
__device__ __forceinline__ void load16_v2(const float* __restrict__ X, size_t rA, size_t rB,
                                          v2f (&x)[16]) {
    float a[16], b[16];
    load16(X, rA, a);
    load16(X, rB, b);
#pragma unroll
    for (int k = 0; k < 16; ++k) { x[k].x = a[k]; x[k].y = b[k]; }
}

__device__ __forceinline__ void store16_lane(float* __restrict__ X, size_t r,
                                             const v2f (&x)[16], int lane) {
    float4* p4 = reinterpret_cast<float4*>(X) + r * 4;
    if (lane == 0) {
        p4[0] = make_float4(x[0].x, x[1].x, x[2].x, x[3].x);
        p4[1] = make_float4(x[4].x, x[5].x, x[6].x, x[7].x);
        p4[2] = make_float4(x[8].x, x[9].x, x[10].x, x[11].x);
        p4[3] = make_float4(x[12].x, x[13].x, x[14].x, x[15].x);
    } else {
        p4[0] = make_float4(x[0].y, x[1].y, x[2].y, x[3].y);
        p4[1] = make_float4(x[4].y, x[5].y, x[6].y, x[7].y);
        p4[2] = make_float4(x[8].y, x[9].y, x[10].y, x[11].y);
        p4[3] = make_float4(x[12].y, x[13].y, x[14].y, x[15].y);
    }
}

// 2-row MLP as v2f: e = tanh(W2 @ tanh(W1 @ x + b1) + b2)
__device__ __forceinline__ void emb16_v2(const v2f (&x)[16],
                                         const float* __restrict__ W1, const float* __restrict__ b1,
                                         const float* __restrict__ W2, const float* __restrict__ b2,
                                         v2f (&e)[16]) {
    v2f h[16];
#pragma unroll
    for (int i = 0; i < 16; ++i) {
        v2f a = vbc(b1[i]);
#pragma unroll
        for (int k = 0; k < 16; ++k) a = vfma(W1[i * 16 + k], x[k], a);
        h[i] = vtanh(a);
    }
#pragma unroll
    for (int i = 0; i < 16; ++i) {
        v2f a = vbc(b2[i]);
#pragma unroll
        for (int k = 0; k < 16; ++k) a = vfma(W2[i * 16 + k], h[k], a);
        e[i] = vtanh(a);
    }
}

// logit = tanh(qk + Wr @ e) . V for a packed row-pair
__device__ __forceinline__ v2f att_logit_v2(const v2f (&e)[16], const float (&qk)[16],
                                            const float* __restrict__ Wr,
                                            const float* __restrict__ V) {
    v2f acc = vbc(0.0f);
#pragma unroll
    for (int i = 0; i < 16; ++i) {
        v2f r = vbc(qk[i]);
#pragma unroll
        for (int k = 0; k < 16; ++k) r = vfma(Wr[i * 16 + k], e[k], r);
        acc = vfma2(vbc(V[i]), vtanh(r), acc);
    }
    return acc;
}

__device__ __forceinline__ float wave_reduce_sum(float v) {
#pragma unroll
    for (int off = 32; off > 0; off >>= 1) v += __shfl_xor(v, off, 64);
    return v;
}

__device__ __forceinline__ void wave_reduce_argmax(float &v, int &idx) {
#pragma unroll
    for (int off = 32; off > 0; off >>= 1) {
        float ov = __shfl_xor(v, off, 64);
        int oi = __shfl_xor(idx, off, 64);
        if (ov > v || (ov == v && oi < idx)) { v = ov; idx = oi; }
    }
}

__device__ __forceinline__ float block_sum(float v) {
    __shared__ float sm[4];
    v = wave_reduce_sum(v);
    __syncthreads();
    if ((threadIdx.x & 63) == 0) sm[threadIdx.x >> 6] = v;
    __syncthreads();
    float r = sm[0] + sm[1] + sm[2] + sm[3];
    __syncthreads();
    return r;
}

__device__ __forceinline__ void block_argmax(float &v, int &i) {
    __shared__ float sv[4];
    __shared__ int si[4];
    wave_reduce_argmax(v, i);
    __syncthreads();
    if ((threadIdx.x & 63) == 0) { sv[threadIdx.x >> 6] = v; si[threadIdx.x >> 6] = i; }
    __syncthreads();
    float bv = sv[0]; int bi = si[0];
#pragma unroll
    for (int k = 1; k < 4; ++k)
        if (sv[k] > bv || (sv[k] == bv && si[k] < bi)) { bv = sv[k]; bi = si[k]; }
    v = bv; i = bi;
    __syncthreads();
}

// reduce (l, s[16]) across the block, write 17 floats to dst; ends synced
__device__ __forceinline__ void block_sum17(float l, float (&s)[16], float* dst) {
    l = wave_reduce_sum(l);
#pragma unroll
    for (int i = 0; i < 16; ++i) s[i] = wave_reduce_sum(s[i]);
    __shared__ float red[4][17];
    int w = threadIdx.x >> 6, ln = threadIdx.x & 63;
    if (ln == 0) {
        red[w][0] = l;
#pragma unroll
        for (int i = 0; i < 16; ++i) red[w][1 + i] = s[i];
    }
    __syncthreads();
    if (threadIdx.x < 17)
        dst[threadIdx.x] = red[0][threadIdx.x] + red[1][threadIdx.x] + red[2][threadIdx.x] + red[3][threadIdx.x];
    __syncthreads();
}

__device__ __forceinline__ void block_argmax_sum_store(float best, int bi, float l,
                                                       float* S, int bid) {
    l = wave_reduce_sum(l);
    wave_reduce_argmax(best, bi);
    __shared__ float rl[4], rv[4];
    __shared__ int ri[4];
    int w = threadIdx.x >> 6, ln = threadIdx.x & 63;
    if (ln == 0) { rl[w] = l; rv[w] = best; ri[w] = bi; }
    __syncthreads();
    if (threadIdx.x == 0) {
        float L = rl[0] + rl[1] + rl[2] + rl[3];
        float v = rv[0]; int i = ri[0];
#pragma unroll
        for (int k = 1; k < 4; ++k)
            if (rv[k] > v || (rv[k] == v && ri[k] < i)) { v = rv[k]; i = ri[k]; }
        S[P2V + bid] = v;
        S[P2I + bid] = (float)i;   // exact: i < 2^24
        S[P2L + bid] = L;
    }
    __syncthreads();
}

// last-block-done arrive: returns true in ALL threads of the final block.
__device__ __forceinline__ bool arrive_last(int* counter, int total) {
    __shared__ int lastFlag;
    if (threadIdx.x == 0) {
        __threadfence();
        int old = atomicAdd(counter, 1);
        lastFlag = (old == total - 1) ? 1 : 0;
    }
    __syncthreads();
    bool last = (lastFlag != 0);
    if (last) __threadfence();   // acquire before reading other blocks' data
    return last;
}

// ---------------------------------------------------------------------------
// combine bodies (run by the LAST block of the preceding phase)
// ---------------------------------------------------------------------------
__device__ void combine_g_device(const Params& p, int phase) {
    const float* PJ = p.S + P1J;
    const float* PM = p.S + P1M;
    float accJ[17], accM[17];
#pragma unroll
    for (int c = 0; c < 17; ++c) { accJ[c] = 0.0f; accM[c] = 0.0f; }
    for (int i = threadIdx.x; i < GJ; i += BLK)
#pragma unroll
        for (int c = 0; c < 17; ++c) accJ[c] += PJ[i * 17 + c];
    for (int i = threadIdx.x; i < GM; i += BLK)
#pragma unroll
        for (int c = 0; c < 17; ++c) accM[c] += PM[i * 17 + c];

    __shared__ float totJ[17], totM[17];
    for (int c = 0; c < 17; ++c) {
        float t = block_sum(accJ[c]);
        if (threadIdx.x == 0) totJ[c] = t;
        t = block_sum(accM[c]);
        if (threadIdx.x == 0) totM[c] = t;
    }
    __syncthreads();

    __shared__ float cb[48], gbuf[16];
    if (threadIdx.x < 16) {
        int i = threadIdx.x;
        cb[i]      = phase ? p.S[S_EJS + i] : p.last_j[i];
        cb[16 + i] = totJ[1 + i] / totJ[0];   // softmax-weighted sum / partition
        cb[32 + i] = totM[1 + i] / totM[0];
    }
    __syncthreads();
    const float* gW  = phase ? p.g2W : p.g1W;
    const float* gbv = phase ? p.g2b : p.g1b;
    if (threadIdx.x < 16) {
        int i = threadIdx.x;
        float a = gbv[i];
#pragma unroll
        for (int k = 0; k < 48; ++k) a = fmaf(gW[i * 48 + k], cb[k], a);
        gbuf[i] = fast_tanh(a);
    }
    __syncthreads();
    const float* Wq = phase ? p.ma_Wq : p.ja_Wq;
    const float* bq = phase ? p.ma_bq : p.ja_bq;
    const int off = phase ? S_QKMA : S_QKJA;
    if (threadIdx.x < 16) {
        int i = threadIdx.x;
        float a = bq[i];
#pragma unroll
        for (int k = 0; k < 16; ++k) a = fmaf(Wq[i * 16 + k], gbuf[k], a);
        p.S[off + i] = a;
    }
}

__device__ void combine2_device(const Params& p) {
    float v = -3.4e38f; int vi = 0x7fffffff; float l = 0.0f;
    for (int i = threadIdx.x; i < GJ; i += BLK) {
        float pv = p.S[P2V + i];
        int pi = (int)p.S[P2I + i];
        if (pv > v || (pv == v && pi < vi)) { v = pv; vi = pi; }
        l += p.S[P2L + i];
    }
    l = block_sum(l);
    block_argmax(v, vi);
    const int sel = vi;

    __shared__ float xb[16], hb[16], eb[16];
    if (threadIdx.x < 16) xb[threadIdx.x] = p.jobs[(size_t)sel * 16 + threadIdx.x];
    __syncthreads();
    if (threadIdx.x < 16) {
        int i = threadIdx.x;
        float a = p.jb1[i];
#pragma unroll
        for (int k = 0; k < 16; ++k) a = fmaf(p.jW1[i * 16 + k], xb[k], a);
        hb[i] = fast_tanh(a);
    }
    __syncthreads();
    if (threadIdx.x < 16) {
        int i = threadIdx.x;
        float a = p.jb2[i];
#pragma unroll
        for (int k = 0; k < 16; ++k) a = fmaf(p.jW2[i * 16 + k], hb[k], a);
        float e = fast_tanh(a);
        eb[i] = e;
        p.S[S_EJS + i] = e;
    }
    __syncthreads();
    if (threadIdx.x < 16) {
        int i = threadIdx.x;
        float a1 = p.aj_bq[i], a2 = p.am_bq[i];
#pragma unroll
        for (int k = 0; k < 16; ++k) {
            a1 = fmaf(p.aj_Wq[i * 16 + k], eb[k], a1);
            a2 = fmaf(p.am_Wq[i * 16 + k], eb[k], a2);
        }
        p.S[S_QK2J + i] = a1;
        p.S[S_QK2M + i] = a2;
    }
    if (threadIdx.x == 0) {
        p.S[S_LOGPJ] = v - logf(l);     // log_softmax at the argmax
        p.S[S_SELJ] = (float)sel;
    }
}

__device__ void final_device(const Params& p) {
    float v = -3.4e38f; int vi = 0x7fffffff; float l = 0.0f;
    for (int i = threadIdx.x; i < GM; i += BLK) {
        float pv = p.S[P2V + i];
        int pi = (int)p.S[P2I + i];
        if (pv > v || (pv == v && pi < vi)) { v = pv; vi = pi; }
        l += p.S[P2L + i];
    }
    l = block_sum(l);
    block_argmax(v, vi);
    if (threadIdx.x == 0) {
        p.out[0] = p.S[S_SELJ];
        p.out[1] = (float)vi;
        p.out[2] = p.S[S_LOGPJ] + (v - logf(l));
    }
}

// ---------------------------------------------------------------------------
// K1: embeddings (+cache) + glimpse-1 partials; last block -> g1 -> S_QKJA.
// blocks [0,GJ) jobs, [GJ,G1) machines. 2 rows/thread (rA, rA+256).
// ---------------------------------------------------------------------------
template <bool CACHE>
__global__ __launch_bounds__(BLK) void k_p1(Params p) {
    const int bid = (int)blockIdx.x;
    const int tid = (int)threadIdx.x;
    const bool isJob = bid < GJ;
    const float* X  = isJob ? p.jobs : p.machines;
    const float* W1 = isJob ? p.jW1 : p.mW1;
    const float* b1 = isJob ? p.jb1 : p.mb1;
    const float* W2 = isJob ? p.jW2 : p.mW2;
    const float* b2 = isJob ? p.jb2 : p.mb2;
    const float* Wg = isJob ? p.aj_Wr : p.am_Wr;
    const float* Vg = isJob ? p.aj_V  : p.am_V;
    float* E = isJob ? p.Ej : p.Em;
    const int n  = isJob ? NJ : NM;
    const int b0 = isJob ? bid : bid - GJ;

    __shared__ float qk1s[16];
    if (tid < 16) {
        const float* Wq = isJob ? p.aj_Wq : p.am_Wq;
        const float* bq = isJob ? p.aj_bq : p.am_bq;
        float a = bq[tid];
#pragma unroll
        for (int k = 0; k < 16; ++k) a = fmaf(Wq[tid * 16 + k], p.last_j[k], a);
        qk1s[tid] = a;
    }
    __syncthreads();
    float qk[16];
#pragma unroll
    for (int i = 0; i < 16; ++i) qk[i] = qk1s[i];
    __syncthreads();

    const int rA = b0 * RPB + tid;
    const int rB = rA + BLK;
    const bool vA = rA < n, vB = rB < n;
    const size_t aA = (size_t)(vA ? rA : 0);
    const size_t aB = (size_t)(vB ? rB : 0);

    v2f x[16], e[16];
    load16_v2(X, aA, aB, x);
    emb16_v2(x, W1, b1, W2, b2, e);
    if (CACHE) {
        if (vA) store16_lane(E, aA, e, 0);
        if (vB) store16_lane(E, aB, e, 1);
    }
    v2f lg = att_logit_v2(e, qk, Wg, Vg);
    // |logit| <= sum|V| ~ 0.6 -> exp never overflows; no max-shift needed.
    v2f pw;
    pw.x = vA ? __expf(lg.x) : 0.0f;
    pw.y = vB ? __expf(lg.y) : 0.0f;
    float l = pw.x + pw.y;
    float s[16];
#pragma unroll
    for (int i = 0; i < 16; ++i) {
        v2f t = pw * e[i];
        s[i] = t.x + t.y;
    }
    block_sum17(l, s, p.S + (isJob ? P1J : P1M) + (size_t)b0 * 17);

    if (arrive_last(p.cnt + 0, G1)) combine_g_device(p, 0);
}

// ---------------------------------------------------------------------------
// K3: job pointer logits -> masked argmax + sum-exp; last block -> combine2.
// ---------------------------------------------------------------------------
template <bool CACHE>
__global__ __launch_bounds__(BLK) void k_p3(Params p) {
    const int bid = (int)blockIdx.x;
    const int tid = (int)threadIdx.x;
    float qk[16];
#pragma unroll
    for (int i = 0; i < 16; ++i) qk[i] = p.S[S_QKJA + i];

    const int rA = bid * RPB + tid;
    const int rB = rA + BLK;
    const bool vA = rA < NJ, vB = rB < NJ;
    const size_t aA = (size_t)(vA ? rA : 0);
    const size_t aB = (size_t)(vB ? rB : 0);

    v2f e[16];
    if (CACHE) {
        load16_v2(p.Ej, aA, aB, e);
    } else {
        v2f x[16];
        load16_v2(p.jobs, aA, aB, x);
        emb16_v2(x, p.jW1, p.jb1, p.jW2, p.jb2, e);
    }
    v2f lg = att_logit_v2(e, qk, p.ja_Wr, p.ja_V);
    const bool mA = vA && (p.mask[aA] != 0);
    const bool mB = vB && (p.mask[aB] != 0);
    float l = (mA ? __expf(lg.x) : 0.0f) + (mB ? __expf(lg.y) : 0.0f);
    // candidates in ascending index order, strict > => smallest index on ties
    float best = mA ? lg.x : NEGV - 1.0f;
    int bi = rA;
    float c = mB ? lg.y : NEGV - 1.0f;
    if (c > best) { best = c; bi = rB; }

    block_argmax_sum_store(best, bi, l, p.S, bid);

    if (arrive_last(p.cnt + 1, GJ)) combine2_device(p);
}

// ---------------------------------------------------------------------------
// K5: glimpse-2 (query e_js); last block -> g2 -> S_QKMA. P1-style role split.
// ---------------------------------------------------------------------------
template <bool CACHE>
__global__ __launch_bounds__(BLK) void k_p5(Params p) {
    const int bid = (int)blockIdx.x;
    const int tid = (int)threadIdx.x;
    const bool isJob = bid < GJ;
    const float* X  = isJob ? p.jobs : p.machines;
    const float* W1 = isJob ? p.jW1 : p.mW1;
    const float* b1 = isJob ? p.jb1 : p.mb1;
    const float* W2 = isJob ? p.jW2 : p.mW2;
    const float* b2 = isJob ? p.jb2 : p.mb2;
    const float* Wg = isJob ? p.aj_Wr : p.am_Wr;
    const float* Vg = isJob ? p.aj_V  : p.am_V;
    const float* E  = isJob ? p.Ej : p.Em;
    const int n  = isJob ? NJ : NM;
    const int b0 = isJob ? bid : bid - GJ;

    float qk[16];
    {
        const float* src = p.S + (isJob ? S_QK2J : S_QK2M);
#pragma unroll
        for (int i = 0; i < 16; ++i) qk[i] = src[i];
    }

    const int rA = b0 * RPB + tid;
    const int rB = rA + BLK;
    const bool vA = rA < n, vB = rB < n;
    const size_t aA = (size_t)(vA ? rA : 0);
    const size_t aB = (size_t)(vB ? rB : 0);

    v2f e[16];
    if (CACHE) {
        load16_v2(E, aA, aB, e);
    } else {
        v2f x[16];
        load16_v2(X, aA, aB, x);
        emb16_v2(x, W1, b1, W2, b2, e);
    }
    v2f lg = att_logit_v2(e, qk, Wg, Vg);
    v2f pw;
    pw.x = vA ? __expf(lg.x) : 0.0f;
    pw.y = vB ? __expf(lg.y) : 0.0f;
    float l = pw.x + pw.y;
    float s[16];
#pragma unroll
    for (int i = 0; i < 16; ++i) {
        v2f t = pw * e[i];
        s[i] = t.x + t.y;
    }
    block_sum17(l, s, p.S + (isJob ? P1J : P1M) + (size_t)b0 * 17);

    if (arrive_last(p.cnt + 2, G1)) combine_g_device(p, 1);
}

// ---------------------------------------------------------------------------
// K7: machine logits -> argmax + sum-exp; last block -> final output.
// ---------------------------------------------------------------------------
template <bool CACHE>
__global__ __launch_bounds__(BLK) void k_p7(Params p) {
    const int bid = (int)blockIdx.x;
    const int tid = (int)threadIdx.x;
    float qk[16];
#pragma unroll
    for (int i = 0; i < 16; ++i) qk[i] = p.S[S_QKMA + i];

    const int rA = bid * RPB + tid;
    const int rB = rA + BLK;
    const bool vA = rA < NM, vB = rB < NM;
    const size_t aA = (size_t)(vA ? rA : 0);
    const size_t aB = (size_t)(vB ? rB : 0);

    v2f e[16];
    if (CACHE) {
        load16_v2(p.Em, aA, aB, e);
    } else {
        v2f x[16];
        load16_v2(p.machines, aA, aB, x);
        emb16_v2(x, p.mW1, p.mb1, p.mW2, p.mb2, e);
    }
    v2f lg = att_logit_v2(e, qk, p.ma_Wr, p.ma_V);
    float l = (vA ? __expf(lg.x) : 0.0f) + (vB ? __expf(lg.y) : 0.0f);
    float best = vA ? lg.x : -3.4e38f;
    int bi = rA;
    float c = vB ? lg.y : -3.4e38f;
    if (c > best) { best = c; bi = rB; }

    block_argmax_sum_store(best, bi, l, p.S, bid);

    if (arrive_last(p.cnt + 3, GM)) final_device(p);
}

// ---------------------------------------------------------------------------
extern "C" void kernel_launch(void* const* d_in, const int* in_sizes, int n_in,
                              void* d_out, int out_size, void* d_ws, size_t ws_size,
                              hipStream_t stream) {
    Params p;
    p.jobs     = (const float*)d_in[0];
    p.machines = (const float*)d_in[1];
    p.mask     = (const int*)d_in[2];
    p.jW1 = (const float*)d_in[3];  p.jb1 = (const float*)d_in[4];
    p.jW2 = (const float*)d_in[5];  p.jb2 = (const float*)d_in[6];
    p.mW1 = (const float*)d_in[7];  p.mb1 = (const float*)d_in[8];
    p.mW2 = (const float*)d_in[9];  p.mb2 = (const float*)d_in[10];
    p.aj_Wq = (const float*)d_in[11]; p.aj_bq = (const float*)d_in[12];
    p.aj_Wr = (const float*)d_in[13]; p.aj_V  = (const float*)d_in[14];
    p.am_Wq = (const float*)d_in[15]; p.am_bq = (const float*)d_in[16];
    p.am_Wr = (const float*)d_in[17]; p.am_V  = (const float*)d_in[18];
    p.ja_Wq = (const float*)d_in[19]; p.ja_bq = (const float*)d_in[20];
    p.ja_Wr = (const float*)d_in[21]; p.ja_V  = (const float*)d_in[22];
    p.ma_Wq = (const float*)d_in[23]; p.ma_bq = (const float*)d_in[24];
    p.ma_Wr = (const float*)d_in[25]; p.ma_V  = (const float*)d_in[26];
    p.g1W = (const float*)d_in[27]; p.g1b = (const float*)d_in[28];
    p.g2W = (const float*)d_in[29]; p.g2b = (const float*)d_in[30];
    p.last_j = (const float*)d_in[31];
    p.S   = (float*)d_ws;
    p.cnt = (int*)((float*)d_ws + S_CNT);
    p.Ej  = (float*)d_ws + E_OFF;
    p.Em  = p.Ej + (size_t)NJ * 16;
    p.out = (float*)d_out;

    const size_t needed = (E_OFF + (size_t)(NJ + NM) * 16) * sizeof(float);
    const bool cache = ws_size >= needed;

    // zero the 4 arrive counters (ws is poisoned 0xAA before every launch)
    hipMemsetAsync((void*)p.cnt, 0, 4 * sizeof(int), stream);

    if (cache) {
        k_p1<true><<<G1, BLK, 0, stream>>>(p);
        k_p3<true><<<GJ, BLK, 0, stream>>>(p);
        k_p5<true><<<G1, BLK, 0, stream>>>(p);
        k_p7<true><<<GM, BLK, 0, stream>>>(p);
    } else {
        k_p1<false><<<G1, BLK, 0, stream>>>(p);
        k_p3<false><<<GJ, BLK, 0, stream>>>(p);
        k_p5<false><<<G1, BLK, 0, stream>>>(p);
        k_p7<false><<<GM, BLK, 0, stream>>>(p);
    }
}